// Round 1
// baseline (344.046 us; speedup 1.0000x reference)
//
#include <hip/hip_runtime.h>
#include <hip/hip_bf16.h>

#define NB   4      // batch
#define CIN  512    // in channels
#define NPX  16384  // H*W
#define KC   256    // key channels
#define KP   150    // proxy regions
#define KPP  160    // padded KP (K-dim multiple of 32)

typedef __attribute__((ext_vector_type(8))) short short8;
typedef __attribute__((ext_vector_type(4))) float f32x4;
typedef unsigned short u16;

__device__ __forceinline__ u16 f2bf(float f) {
    unsigned int u = __float_as_uint(f);
    unsigned int r = (u + 0x7FFFu + ((u >> 16) & 1u)) >> 16;
    return (u16)r;
}

__device__ __forceinline__ u16 ld_bf(const float* p) { return f2bf(*p); }
__device__ __forceinline__ u16 ld_bf(const u16* p)   { return *p; }

__device__ __forceinline__ void store_out(float* p, float v) { *p = v; }
__device__ __forceinline__ void store_out(u16* p, float v)   { *p = f2bf(v); }

// ---------------------------------------------------------------------------
// Unified GEMM:  Out[m][n] = act( (sum_k A[m][k]*In[k][n]) * scale + bias[m] )
//                optionally * colscale[b][n], optional relu.
// A: bf16 [>=gridY*128][lda], per-batch stride strideAb (0 = shared weights)
// In: [K][N] per batch (fp32 or bf16), batch stride K*N
// Out: [M_out][N] per batch, rows >= M_out skipped
// Tile: BM=BN=128, BK=32. 256 threads = 4 waves (2x2), each wave 64x64.
// LDS: As[n][40]/Bs[n][40] padded stride (80B) -> b128 frag reads, low conflict.
// ---------------------------------------------------------------------------
template<typename IN_T, typename OUT_T, bool RELU, bool HASBIAS, bool HASCS>
__global__ __launch_bounds__(256, 2)
void gemm_kernel(const u16* __restrict__ A,
                 const IN_T* __restrict__ In,
                 OUT_T* __restrict__ Out,
                 const float* __restrict__ bias,
                 const float* __restrict__ cs,
                 int M_out, int N, int K, int lda, long strideAb, float scale)
{
    const int b  = blockIdx.z;
    const int n0 = blockIdx.x * 128;
    const int m0 = blockIdx.y * 128;
    A   += (long)b * strideAb;
    In  += (long)b * (long)K * (long)N;
    Out += (long)b * (long)M_out * (long)N;

    __shared__ u16 As[128][40];   // [m][k], stride 80B
    __shared__ u16 Bs[128][40];   // [n][k], stride 80B

    const int tid  = threadIdx.x;
    const int lane = tid & 63;
    const int wid  = tid >> 6;
    const int wr = wid >> 1, wc = wid & 1;

    f32x4 acc[4][4];
    #pragma unroll
    for (int i = 0; i < 4; ++i)
        #pragma unroll
        for (int j = 0; j < 4; ++j)
            acc[i][j] = (f32x4){0.f, 0.f, 0.f, 0.f};

    const int arow = tid >> 1, akh = tid & 1;     // A stage mapping
    const int bnn  = tid & 127, bkh = tid >> 7;   // B stage mapping

    for (int k0 = 0; k0 < K; k0 += 32) {
        // ---- stage A tile (rows k-contiguous in global, vector copy) ----
        {
            const u16* src = A + (long)(m0 + arow) * lda + (k0 + akh * 16);
            uint4 v0 = *(const uint4*)src;
            uint4 v1 = *(const uint4*)(src + 8);
            *(uint4*)&As[arow][akh * 16]     = v0;
            *(uint4*)&As[arow][akh * 16 + 8] = v1;
        }
        // ---- stage B tile transposed: gather column n over 16 k-rows ----
        {
            const IN_T* src = In + (long)(k0 + bkh * 16) * N + (n0 + bnn);
            u16 tmp[16];
            #pragma unroll
            for (int j = 0; j < 16; ++j)
                tmp[j] = ld_bf(src + (long)j * N);
            *(uint4*)&Bs[bnn][bkh * 16]     = *(uint4*)&tmp[0];
            *(uint4*)&Bs[bnn][bkh * 16 + 8] = *(uint4*)&tmp[8];
        }
        __syncthreads();

        const int rg = lane & 15, kg = lane >> 4;
        short8 af[4], bfr[4];
        #pragma unroll
        for (int i = 0; i < 4; ++i) {
            af[i]  = *(const short8*)&As[wr * 64 + i * 16 + rg][kg * 8];
            bfr[i] = *(const short8*)&Bs[wc * 64 + i * 16 + rg][kg * 8];
        }
        #pragma unroll
        for (int i = 0; i < 4; ++i)
            #pragma unroll
            for (int j = 0; j < 4; ++j)
                acc[i][j] = __builtin_amdgcn_mfma_f32_16x16x32_bf16(af[i], bfr[j], acc[i][j], 0, 0, 0);
        __syncthreads();
    }

    // ---- epilogue: D mapping col=lane&15, row=(lane>>4)*4+r (m89-verified) ----
    const int cl = lane & 15, rq = lane >> 4;
    #pragma unroll
    for (int j = 0; j < 4; ++j) {
        const int col = n0 + wc * 64 + j * 16 + cl;
        float csv = 1.f;
        if (HASCS) csv = cs[(long)b * N + col];
        #pragma unroll
        for (int i = 0; i < 4; ++i) {
            #pragma unroll
            for (int r = 0; r < 4; ++r) {
                int row = m0 + wr * 64 + i * 16 + rq * 4 + r;
                if (row < M_out) {
                    float v = acc[i][j][r] * scale;
                    if (HASBIAS) v += bias[row];
                    if (HASCS)   v *= csv;
                    if (RELU)    v = fmaxf(v, 0.f);
                    store_out(&Out[(long)row * N + col], v);
                }
            }
        }
    }
}

// ---------------------------------------------------------------------------
// kv1: hidden_o[b][kc][kp] = relu(w_o1 . proxy + b_o1)   (fp32, KPP stride)
//      vT[b][kc][kp]       = relu(w_d  . proxy + b_d)    (bf16, KPP stride, pad=0)
// ---------------------------------------------------------------------------
__global__ void kv1_kernel(const float* __restrict__ proxy,
                           const float* __restrict__ w_o1, const float* __restrict__ b_o1,
                           const float* __restrict__ w_d,  const float* __restrict__ b_d,
                           float* __restrict__ hidden_o, u16* __restrict__ vT)
{
    const int kc = blockIdx.x;
    const int b  = blockIdx.y;
    const int kp = threadIdx.x;   // 0..159
    float ah = 0.f, av = 0.f;
    if (kp < KP) {
        const float* px = proxy + (long)b * CIN * KP + kp;
        const float* w1 = w_o1 + (long)kc * CIN;
        const float* wd = w_d  + (long)kc * CIN;
        for (int c = 0; c < CIN; ++c) {
            float p = px[(long)c * KP];
            ah += w1[c] * p;
            av += wd[c] * p;
        }
        ah = fmaxf(ah + b_o1[kc], 0.f);
        av = fmaxf(av + b_d[kc], 0.f);
    }
    long o = ((long)b * KC + kc) * KPP + kp;
    hidden_o[o] = ah;
    vT[o] = (kp < KP) ? f2bf(av) : (u16)0;
}

// ---------------------------------------------------------------------------
// kv2: keyT[b][kp][kc] = relu(w_o2 . hidden_o[:, kp] + b_o2), rows kp>=150 -> 0
// keyT padded to 256 rows (zeros) so G3 can run a full 128-row second tile.
// ---------------------------------------------------------------------------
__global__ void kv2_kernel(const float* __restrict__ hidden_o,
                           const float* __restrict__ w_o2, const float* __restrict__ b_o2,
                           u16* __restrict__ keyT)
{
    const int kp = blockIdx.x;   // 0..255
    const int b  = blockIdx.y;
    const int kc = threadIdx.x;  // 0..255
    long o = ((long)b * 256 + kp) * 256 + kc;
    if (kp >= KP) { keyT[o] = 0; return; }
    const float* w = w_o2 + (long)kc * KC;
    const float* h = hidden_o + (long)b * KC * KPP + kp;
    float acc = 0.f;
    for (int c = 0; c < KC; ++c)
        acc += w[c] * h[(long)c * KPP];
    keyT[o] = f2bf(fmaxf(acc + b_o2[kc], 0.f));
}

// ---------------------------------------------------------------------------
// softmax over KP dim of simT[b][160][N] (rows 150..159 ignored).
// Writes unnormalized exp as bf16 P (pad rows zeroed) + 1/sumexp per column.
// Column-parallel: consecutive threads read consecutive n -> fully coalesced.
// ---------------------------------------------------------------------------
__global__ void softmax_kernel(const float* __restrict__ simT,
                               u16* __restrict__ P,
                               float* __restrict__ linv, int N)
{
    const long n = (long)blockIdx.x * 256 + threadIdx.x;
    const int  b = blockIdx.y;
    const float* s = simT + (long)b * KPP * N + n;
    u16* p = P + (long)b * KPP * N + n;
    float m = -1e30f;
    for (int k = 0; k < KP; ++k) m = fmaxf(m, s[(long)k * N]);
    float l = 0.f;
    for (int k = 0; k < KP; ++k) {
        float e = __expf(s[(long)k * N] - m);
        l += e;
        p[(long)k * N] = f2bf(e);
    }
    for (int k = KP; k < KPP; ++k) p[(long)k * N] = 0;
    linv[(long)b * N + n] = 1.f / l;
}

// fp32 -> bf16 conversion of the three shared weight matrices
__global__ void prep_w(const float* __restrict__ w1, const float* __restrict__ w2,
                       const float* __restrict__ w3,
                       u16* __restrict__ o1, u16* __restrict__ o2, u16* __restrict__ o3)
{
    int i = blockIdx.x * 256 + threadIdx.x;
    if (i < KC * CIN) o1[i] = f2bf(w1[i]);
    if (i < KC * KC)  o2[i] = f2bf(w2[i]);
    if (i < CIN * KC) o3[i] = f2bf(w3[i]);
}

extern "C" void kernel_launch(void* const* d_in, const int* in_sizes, int n_in,
                              void* d_out, int out_size, void* d_ws, size_t ws_size,
                              hipStream_t stream)
{
    const float* x     = (const float*)d_in[0];
    const float* proxy = (const float*)d_in[1];
    const float* w_p1  = (const float*)d_in[2];
    const float* b_p1  = (const float*)d_in[3];
    const float* w_p2  = (const float*)d_in[4];
    const float* b_p2  = (const float*)d_in[5];
    const float* w_o1  = (const float*)d_in[6];
    const float* b_o1  = (const float*)d_in[7];
    const float* w_o2  = (const float*)d_in[8];
    const float* b_o2  = (const float*)d_in[9];
    const float* w_d   = (const float*)d_in[10];
    const float* b_d   = (const float*)d_in[11];
    const float* w_u   = (const float*)d_in[12];
    const float* b_u   = (const float*)d_in[13];
    float* out = (float*)d_out;

    char* ws = (char*)d_ws;
    size_t off = 0;
    auto alloc = [&](size_t bytes) { size_t o = off; off += (bytes + 255) & ~(size_t)255; return o; };

    u16*   wb_p1    = (u16*)  (ws + alloc((size_t)KC * CIN * 2));
    u16*   wb_p2    = (u16*)  (ws + alloc((size_t)KC * KC * 2));
    u16*   wb_u     = (u16*)  (ws + alloc((size_t)CIN * KC * 2));
    u16*   keyT     = (u16*)  (ws + alloc((size_t)NB * 256 * 256 * 2));
    u16*   vT       = (u16*)  (ws + alloc((size_t)NB * KC * KPP * 2));
    float* hidden_o = (float*)(ws + alloc((size_t)NB * KC * KPP * 4));
    u16*   h1       = (u16*)  (ws + alloc((size_t)NB * KC * NPX * 2));  // reused as context
    u16*   q2       = (u16*)  (ws + alloc((size_t)NB * KC * NPX * 2));
    float* simT     = (float*)(ws + alloc((size_t)NB * KPP * NPX * 4));
    u16*   Pbuf     = (u16*)  (ws + alloc((size_t)NB * KPP * NPX * 2));
    float* linv     = (float*)(ws + alloc((size_t)NB * NPX * 4));
    (void)ws_size; (void)in_sizes; (void)n_in; (void)out_size;

    // weights -> bf16
    prep_w<<<512, 256, 0, stream>>>(w_p1, w_p2, w_u, wb_p1, wb_p2, wb_u);
    // key/value projections (tiny)
    kv1_kernel<<<dim3(KC, NB), KPP, 0, stream>>>(proxy, w_o1, b_o1, w_d, b_d, hidden_o, vT);
    kv2_kernel<<<dim3(256, NB), 256, 0, stream>>>(hidden_o, w_o2, b_o2, keyT);

    // G1: h1 = relu(w_p1 . x + b_p1)        M=256 K=512, In fp32
    gemm_kernel<float, u16, true, true, false><<<dim3(NPX / 128, 2, NB), 256, 0, stream>>>(
        wb_p1, x, h1, b_p1, nullptr, 256, NPX, 512, 512, 0, 1.f);
    // G2: q2 = relu(w_p2 . h1 + b_p2)       M=256 K=256
    gemm_kernel<u16, u16, true, true, false><<<dim3(NPX / 128, 2, NB), 256, 0, stream>>>(
        wb_p2, h1, q2, b_p2, nullptr, 256, NPX, 256, 256, 0, 1.f);
    // G3: simT = keyT . q2 * (1/16)         M_out=160 (padded A), K=256, out fp32
    gemm_kernel<u16, float, false, false, false><<<dim3(NPX / 128, 2, NB), 256, 0, stream>>>(
        keyT, q2, simT, nullptr, nullptr, KPP, NPX, 256, 256, (long)256 * 256, 0.0625f);
    // softmax over KP
    softmax_kernel<<<dim3(NPX / 256, NB), 256, 0, stream>>>(simT, Pbuf, linv, NPX);
    // G4: context = vT . P * diag(linv)     M=256 K=160  (h1 buffer reused)
    gemm_kernel<u16, u16, false, false, true><<<dim3(NPX / 128, 2, NB), 256, 0, stream>>>(
        vT, Pbuf, h1, nullptr, linv, 256, NPX, KPP, KPP, (long)KC * KPP, 1.f);
    // G5: out = relu(w_u . context + b_u)   M=512 K=256, out fp32
    gemm_kernel<u16, float, true, true, false><<<dim3(NPX / 128, 4, NB), 256, 0, stream>>>(
        wb_u, h1, out, b_u, nullptr, CIN, NPX, 256, 256, 0, 1.f);
}

// Round 2
// 286.374 us; speedup vs baseline: 1.2014x; 1.2014x over previous
//
#include <hip/hip_runtime.h>
#include <hip/hip_bf16.h>

#define NB   4      // batch
#define CIN  512    // in channels
#define NPX  16384  // H*W
#define KC   256    // key channels
#define KP   150    // proxy regions
#define KPAD 192    // kp padded to multiple of 64

typedef __attribute__((ext_vector_type(8))) short short8;
typedef __attribute__((ext_vector_type(4))) float f32x4;
typedef __attribute__((ext_vector_type(4))) unsigned int u32x4;
typedef unsigned short u16;

__device__ __forceinline__ u16 f2bf(float f) {
    unsigned int u = __float_as_uint(f);
    return (u16)((u + 0x7FFFu + ((u >> 16) & 1u)) >> 16);
}

__device__ __forceinline__ void gload_lds16(const void* g, void* l) {
    __builtin_amdgcn_global_load_lds(
        (const __attribute__((address_space(1))) unsigned int*)g,
        (__attribute__((address_space(3))) unsigned int*)l,
        16, 0, 0);
}

// ---------------------------------------------------------------------------
// NT GEMM: A [M][K] bf16 k-contig (lda), B [NPX][K] bf16 k-contig (ldb).
// Out[m][n] = act( (sum_k A[m][k]*B[n][k]) * scale + bias[m] )
// TRANS_OUT: writes Out[n][m] (ldo = M stride) with 8/16B vector stores.
// Tile 128x128, BK=64, 512 thr = 8 waves (2m x 4n), wave tile 64x32.
// LDS 64KB dbuf; staging via global_load_lds w/ source-side XOR swizzle
// (chunk ^= row&7) so ds_read_b128 frag reads are conflict-free (rule #21).
// 2-phase pipeline (T3 minimum): STAGE(next) -> compute(cur) -> barrier.
// ---------------------------------------------------------------------------
template<typename OUT_T, bool TRANS_OUT, bool RELU, bool HASBIAS>
__global__ __launch_bounds__(512, 4)
void gemm_nt(const u16* __restrict__ A, long strideAb,
             const u16* __restrict__ B,
             OUT_T* __restrict__ Out, long strideOb,
             const float* __restrict__ bias,
             int M_out, int K, int lda, int ldb, int ldo, float scale)
{
    const int bz = blockIdx.z;
    const int n0 = blockIdx.x * 128;
    const int m0 = blockIdx.y * 128;
    A   += (long)bz * strideAb;
    B   += (long)bz * (long)NPX * ldb;
    Out += (long)bz * strideOb;

    __shared__ u16 lds[2][2][128][64];   // [buf][A/B][row][k]

    const int tid  = threadIdx.x;
    const int lane = tid & 63;
    const int wid  = tid >> 6;
    const int wr = wid >> 2;   // 0..1 (m)
    const int wc = wid & 3;    // 0..3 (n)
    const int rg = lane & 15, kg = lane >> 4;
    const int xr = rg & 7;

    f32x4 acc[4][2];
    #pragma unroll
    for (int i = 0; i < 4; ++i)
        #pragma unroll
        for (int j = 0; j < 2; ++j)
            acc[i][j] = (f32x4){0.f, 0.f, 0.f, 0.f};

    // staging: slot = p*512 + tid; row = slot>>3; lds chunk = slot&7;
    // source chunk = ldschunk ^ (row&7)  (involution; row&7 == srow&7 for both p)
    const int srow = tid >> 3;
    const int sgc  = (tid & 7) ^ (srow & 7);
    const u16* Abase = A + (long)(m0 + srow) * lda + sgc * 8;
    const u16* Bbase = B + (long)(n0 + srow) * ldb + sgc * 8;

    const int nt = K >> 6;

    auto STAGE = [&](int buf, int kt) {
        const int k0 = kt << 6;
        #pragma unroll
        for (int p = 0; p < 2; ++p) {
            gload_lds16(Abase + (long)p * 64 * lda + k0,
                        &lds[buf][0][0][0] + (p * 512 + wid * 64) * 8);
            gload_lds16(Bbase + (long)p * 64 * ldb + k0,
                        &lds[buf][1][0][0] + (p * 512 + wid * 64) * 8);
        }
    };

    STAGE(0, 0);
    __syncthreads();

    for (int kt = 0; kt < nt; ++kt) {
        const int buf = kt & 1;
        if (kt + 1 < nt) STAGE(buf ^ 1, kt + 1);
        const u16* As = &lds[buf][0][0][0];
        const u16* Bs = &lds[buf][1][0][0];
        #pragma unroll
        for (int s = 0; s < 2; ++s) {
            const int ch = (((s << 2) + kg) ^ xr) << 3;
            short8 a[4], bq[2];
            #pragma unroll
            for (int i = 0; i < 4; ++i)
                a[i] = *(const short8*)(As + (wr * 64 + i * 16 + rg) * 64 + ch);
            #pragma unroll
            for (int j = 0; j < 2; ++j)
                bq[j] = *(const short8*)(Bs + (wc * 32 + j * 16 + rg) * 64 + ch);
            #pragma unroll
            for (int i = 0; i < 4; ++i)
                #pragma unroll
                for (int j = 0; j < 2; ++j)
                    acc[i][j] = __builtin_amdgcn_mfma_f32_16x16x32_bf16(a[i], bq[j], acc[i][j], 0, 0, 0);
        }
        __syncthreads();
    }

    // epilogue: D mapping col=lane&15 (=rg, n), row=(lane>>4)*4+r (=kg, m)
    #pragma unroll
    for (int i = 0; i < 4; ++i) {
        const int mblk = m0 + wr * 64 + i * 16;
        if (mblk < M_out) {           // M_out is a multiple of 16
            const int rowm = mblk + kg * 4;
            f32x4 bv = (f32x4){0.f, 0.f, 0.f, 0.f};
            if (HASBIAS) bv = *(const f32x4*)(bias + rowm);
            #pragma unroll
            for (int j = 0; j < 2; ++j) {
                const int coln = n0 + wc * 32 + j * 16 + rg;
                f32x4 v = acc[i][j];
                v = v * scale;
                if (HASBIAS) v += bv;
                if (RELU) {
                    v.x = fmaxf(v.x, 0.f); v.y = fmaxf(v.y, 0.f);
                    v.z = fmaxf(v.z, 0.f); v.w = fmaxf(v.w, 0.f);
                }
                if (TRANS_OUT) {
                    if constexpr (sizeof(OUT_T) == 2) {
                        unsigned lo = (unsigned)f2bf(v.x) | ((unsigned)f2bf(v.y) << 16);
                        unsigned hi = (unsigned)f2bf(v.z) | ((unsigned)f2bf(v.w) << 16);
                        uint2 pk; pk.x = lo; pk.y = hi;
                        *(uint2*)((u16*)Out + (long)coln * ldo + rowm) = pk;
                    } else {
                        *(f32x4*)((float*)Out + (long)coln * ldo + rowm) = v;
                    }
                } else {
                    #pragma unroll
                    for (int r = 0; r < 4; ++r) {
                        float f = (r == 0) ? v.x : (r == 1) ? v.y : (r == 2) ? v.z : v.w;
                        if constexpr (sizeof(OUT_T) == 2)
                            ((u16*)Out)[(long)(rowm + r) * ldo + coln] = f2bf(f);
                        else
                            ((float*)Out)[(long)(rowm + r) * ldo + coln] = f;
                    }
                }
            }
        }
    }
}

// ---------------------------------------------------------------------------
// transpose: x [b][512][16384] fp32 -> xT [b][16384][512] bf16. 64x64 tiles.
// LDS [64][73] (odd pad -> 2-way-free banks both phases).
// ---------------------------------------------------------------------------
__global__ __launch_bounds__(256)
void transpose_x(const float* __restrict__ x, u16* __restrict__ xT)
{
    __shared__ u16 t[64][73];
    const int b  = blockIdx.z;
    const int n0 = blockIdx.x * 64, c0 = blockIdx.y * 64;
    const int tid = threadIdx.x;
    const int ln = tid & 63, cq = tid >> 6;
    const float* xp = x + ((long)b * CIN + c0) * NPX + n0 + ln;
    #pragma unroll
    for (int cc = 0; cc < 16; ++cc) {
        const int c = cc * 4 + cq;
        t[c][ln] = f2bf(xp[(long)c * NPX]);
    }
    __syncthreads();
    const int n = tid >> 2, ch = (tid & 3) * 16;
    u16 tmp[16];
    #pragma unroll
    for (int j = 0; j < 16; ++j) tmp[j] = t[ch + j][n];
    u32x4 v0, v1;
    v0.x = tmp[0] | ((unsigned)tmp[1] << 16);  v0.y = tmp[2] | ((unsigned)tmp[3] << 16);
    v0.z = tmp[4] | ((unsigned)tmp[5] << 16);  v0.w = tmp[6] | ((unsigned)tmp[7] << 16);
    v1.x = tmp[8] | ((unsigned)tmp[9] << 16);  v1.y = tmp[10] | ((unsigned)tmp[11] << 16);
    v1.z = tmp[12] | ((unsigned)tmp[13] << 16); v1.w = tmp[14] | ((unsigned)tmp[15] << 16);
    u16* op = xT + ((long)b * NPX + n0 + n) * CIN + c0 + ch;
    *(u32x4*)op = v0;
    *(u32x4*)(op + 8) = v1;
}

// ---------------------------------------------------------------------------
// kv1: hidden[b][kc][kp](fp32, stride 160) = relu(w_o1 . proxy + b_o1)
//      vT[b][kc][kp](bf16, stride 192, pad 0) = relu(w_d . proxy + b_d)
// ---------------------------------------------------------------------------
__global__ void kv1_kernel(const float* __restrict__ proxy,
                           const float* __restrict__ w_o1, const float* __restrict__ b_o1,
                           const float* __restrict__ w_d,  const float* __restrict__ b_d,
                           float* __restrict__ hidden, u16* __restrict__ vT)
{
    const int kc = blockIdx.x;
    const int b  = blockIdx.y;
    const int kp = threadIdx.x;   // 0..191
    float ah = 0.f, av = 0.f;
    if (kp < KP) {
        const float* px = proxy + (long)b * CIN * KP + kp;
        const float* w1 = w_o1 + (long)kc * CIN;
        const float* wd = w_d  + (long)kc * CIN;
        for (int c = 0; c < CIN; ++c) {
            float p = px[(long)c * KP];
            ah += w1[c] * p;
            av += wd[c] * p;
        }
        ah = fmaxf(ah + b_o1[kc], 0.f);
        av = fmaxf(av + b_d[kc], 0.f);
    }
    if (kp < 160) hidden[((long)b * KC + kc) * 160 + kp] = ah;
    vT[((long)b * KC + kc) * KPAD + kp] = f2bf(av);
}

// kv2: keyT[b][kp][kc] (256 rows, zero-padded) = relu(w_o2 . hidden + b_o2)
__global__ void kv2_kernel(const float* __restrict__ hidden,
                           const float* __restrict__ w_o2, const float* __restrict__ b_o2,
                           u16* __restrict__ keyT)
{
    const int kp = blockIdx.x;   // 0..255
    const int b  = blockIdx.y;
    const int kc = threadIdx.x;  // 0..255
    long o = ((long)b * 256 + kp) * 256 + kc;
    if (kp >= KP) { keyT[o] = 0; return; }
    const float* w = w_o2 + (long)kc * KC;
    const float* h = hidden + (long)b * KC * 160 + kp;
    float acc = 0.f;
    for (int c = 0; c < KC; ++c)
        acc += w[c] * h[(long)c * 160];
    keyT[o] = f2bf(fmaxf(acc + b_o2[kc], 0.f));
}

// ---------------------------------------------------------------------------
// softmax over kp of sim[n][192] fp32 (valid 0..149); writes normalized bf16
// P[n][192] (pad zeros). Row-contiguous: vectorized reads, 16B writes.
// ---------------------------------------------------------------------------
__global__ __launch_bounds__(256)
void softmax_kernel(const float* __restrict__ sim, u16* __restrict__ P)
{
    const long n = (long)blockIdx.x * 256 + threadIdx.x;
    const float* s = sim + n * KPAD;
    u16* p = P + n * KPAD;
    float m = -1e30f;
    #pragma unroll 4
    for (int j = 0; j < 37; ++j) {
        f32x4 v = *(const f32x4*)(s + j * 4);
        m = fmaxf(m, fmaxf(fmaxf(v.x, v.y), fmaxf(v.z, v.w)));
    }
    m = fmaxf(m, fmaxf(s[148], s[149]));
    float l = 0.f;
    #pragma unroll 4
    for (int j = 0; j < 37; ++j) {
        f32x4 v = *(const f32x4*)(s + j * 4);
        l += __expf(v.x - m) + __expf(v.y - m) + __expf(v.z - m) + __expf(v.w - m);
    }
    l += __expf(s[148] - m) + __expf(s[149] - m);
    const float inv = 1.f / l;
    #pragma unroll
    for (int j = 0; j < 24; ++j) {
        unsigned d0 = 0, d1 = 0, d2 = 0, d3 = 0;
        if (j < 19) {
            #pragma unroll
            for (int e = 0; e < 8; ++e) {
                const int k = j * 8 + e;
                unsigned bf = 0;
                if (k < KP) bf = f2bf(__expf(s[k] - m) * inv);
                unsigned sh = (e & 1) * 16;
                if (e < 2)      d0 |= bf << sh;
                else if (e < 4) d1 |= bf << sh;
                else if (e < 6) d2 |= bf << sh;
                else            d3 |= bf << sh;
            }
        }
        u32x4 v; v.x = d0; v.y = d1; v.z = d2; v.w = d3;
        *(u32x4*)(p + j * 8) = v;
    }
}

// fp32 -> bf16 conversion of the three shared weight matrices
__global__ void prep_w(const float* __restrict__ w1, const float* __restrict__ w2,
                       const float* __restrict__ w3,
                       u16* __restrict__ o1, u16* __restrict__ o2, u16* __restrict__ o3)
{
    int i = blockIdx.x * 256 + threadIdx.x;
    if (i < KC * CIN) o1[i] = f2bf(w1[i]);
    if (i < KC * KC)  o2[i] = f2bf(w2[i]);
    if (i < CIN * KC) o3[i] = f2bf(w3[i]);
}

extern "C" void kernel_launch(void* const* d_in, const int* in_sizes, int n_in,
                              void* d_out, int out_size, void* d_ws, size_t ws_size,
                              hipStream_t stream)
{
    const float* x     = (const float*)d_in[0];
    const float* proxy = (const float*)d_in[1];
    const float* w_p1  = (const float*)d_in[2];
    const float* b_p1  = (const float*)d_in[3];
    const float* w_p2  = (const float*)d_in[4];
    const float* b_p2  = (const float*)d_in[5];
    const float* w_o1  = (const float*)d_in[6];
    const float* b_o1  = (const float*)d_in[7];
    const float* w_o2  = (const float*)d_in[8];
    const float* b_o2  = (const float*)d_in[9];
    const float* w_d   = (const float*)d_in[10];
    const float* b_d   = (const float*)d_in[11];
    const float* w_u   = (const float*)d_in[12];
    const float* b_u   = (const float*)d_in[13];
    float* out = (float*)d_out;
    (void)in_sizes; (void)n_in; (void)out_size; (void)ws_size;

    char* ws = (char*)d_ws;
    size_t off = 0;
    auto alloc = [&](size_t bytes) { size_t o = off; off += (bytes + 255) & ~(size_t)255; return o; };

    u16*   wb_p1  = (u16*)  (ws + alloc((size_t)KC * CIN * 2));
    u16*   wb_p2  = (u16*)  (ws + alloc((size_t)KC * KC * 2));
    u16*   wb_u   = (u16*)  (ws + alloc((size_t)CIN * KC * 2));
    u16*   keyT   = (u16*)  (ws + alloc((size_t)NB * 256 * 256 * 2));
    u16*   vT     = (u16*)  (ws + alloc((size_t)NB * KC * KPAD * 2));
    float* hidden = (float*)(ws + alloc((size_t)NB * KC * 160 * 4));
    char*  poolA  = ws + alloc((size_t)NB * NPX * CIN * 2);          // 67.1 MB
    u16*   h1     = (u16*)  (ws + alloc((size_t)NB * NPX * KC * 2)); // 33.5 MB
    u16*   q2     = (u16*)  (ws + alloc((size_t)NB * NPX * KC * 2)); // 33.5 MB
    float* sim    = (float*)(ws + alloc((size_t)NB * NPX * KPAD * 4)); // 50.3 MB

    u16* xT      = (u16*)poolA;                  // live: transpose -> G1
    u16* context = (u16*)poolA;                  // live: G4 -> G5 (xT dead)
    u16* Pbuf    = (u16*)(poolA + 35651584);     // live: SM -> G4 (inside xT region)

    prep_w<<<512, 256, 0, stream>>>(w_p1, w_p2, w_u, wb_p1, wb_p2, wb_u);
    transpose_x<<<dim3(NPX / 64, CIN / 64, NB), 256, 0, stream>>>(x, xT);
    kv1_kernel<<<dim3(KC, NB), KPAD, 0, stream>>>(proxy, w_o1, b_o1, w_d, b_d, hidden, vT);
    kv2_kernel<<<dim3(256, NB), 256, 0, stream>>>(hidden, w_o2, b_o2, keyT);

    // G1: h1[n][kc] = relu(w_p1 . xT[n] + b_p1)      M=256 K=512
    gemm_nt<u16, true, true, true><<<dim3(NPX / 128, 2, NB), 512, 0, stream>>>(
        wb_p1, 0, xT, h1, (long)NPX * KC, b_p1, KC, CIN, CIN, CIN, KC, 1.f);
    // G2: q2[n][kc] = relu(w_p2 . h1[n] + b_p2)      M=256 K=256
    gemm_nt<u16, true, true, true><<<dim3(NPX / 128, 2, NB), 512, 0, stream>>>(
        wb_p2, 0, h1, q2, (long)NPX * KC, b_p2, KC, KC, KC, KC, KC, 1.f);
    // G3: sim[n][kp] = (keyT . q2[n]) / 16           M_out=160 K=256, fp32 out
    gemm_nt<float, true, false, false><<<dim3(NPX / 128, 2, NB), 512, 0, stream>>>(
        keyT, (long)256 * 256, q2, sim, (long)NPX * KPAD, nullptr, 160, KC, KC, KC, KPAD, 0.0625f);
    // softmax -> normalized bf16 P[n][192]
    softmax_kernel<<<dim3(NB * NPX / 256), 256, 0, stream>>>(sim, Pbuf);
    // G4: context[n][kc] = vT . P[n]                 M=256 K=192
    gemm_nt<u16, true, false, false><<<dim3(NPX / 128, 2, NB), 512, 0, stream>>>(
        vT, (long)KC * KPAD, Pbuf, context, (long)NPX * KC, nullptr, KC, KPAD, KPAD, KPAD, KC, 1.f);
    // G5: out[c][n] = relu(w_u . context[n] + b_u)   M=512 K=256, fp32 [M][N]
    gemm_nt<float, false, true, true><<<dim3(NPX / 128, 4, NB), 512, 0, stream>>>(
        wb_u, 0, context, out, (long)CIN * NPX, b_u, CIN, KC, KC, KC, NPX, 1.f);
}

// Round 3
// 225.776 us; speedup vs baseline: 1.5238x; 1.2684x over previous
//
#include <hip/hip_runtime.h>
#include <hip/hip_bf16.h>

#define NB   4      // batch
#define CIN  512    // in channels
#define NPX  16384  // H*W
#define KC   256    // key channels
#define KP   150    // proxy regions
#define KVP  192    // kp padded for vT/P (24 chunks)

typedef __attribute__((ext_vector_type(8))) short short8;
typedef __attribute__((ext_vector_type(4))) float f32x4;
typedef __attribute__((ext_vector_type(4))) unsigned int u32x4;
typedef unsigned short u16;

__device__ __forceinline__ u16 f2bf(float f) {
    unsigned int u = __float_as_uint(f);
    return (u16)((u + 0x7FFFu + ((u >> 16) & 1u)) >> 16);
}

__device__ __forceinline__ void gload_lds16(const void* g, void* l) {
    __builtin_amdgcn_global_load_lds(
        (const __attribute__((address_space(1))) unsigned int*)g,
        (__attribute__((address_space(3))) unsigned int*)l,
        16, 0, 0);
}

// swizzle within 8-chunk groups (involution): pos = (c&~7) | ((c&7)^r7)
__device__ __forceinline__ int swz8(int c, int r7) { return (c & ~7) | ((c & 7) ^ r7); }

// ===========================================================================
// kernelA: q2 = relu(W_p2 . relu(W_p1 . xT[n] + b_p1) + b_p2)  per 128-n tile
// LDS 80KB -> 2 blocks/CU. 512 thr = 8 waves, wave n-slice 16.
// ===========================================================================
__global__ __launch_bounds__(512, 4)
void g12_kernel(const u16* __restrict__ wp1, const u16* __restrict__ xtg,
                const u16* __restrict__ wp2, const float* __restrict__ bp1,
                const float* __restrict__ bp2, u16* __restrict__ q2g)
{
    __shared__ u16 sh[40960];          // 80 KB
    u16* WA = sh;                      // [256][8ch]  32KB (G1 A tile)
    u16* XB = sh + 16384;              // [128][8ch]  16KB (G1 B tile)
    u16* H1 = sh;                      // [128][256]  64KB (overlay after G1)
    u16* W2 = sh + 32768;              // [256][4ch]  16KB (G2 A tile)

    const int b  = blockIdx.z;
    const int n0 = blockIdx.x * 128;
    const int tid = threadIdx.x, lane = tid & 63, wid = tid >> 6;
    const int rg = lane & 15, kg = lane >> 4;
    const int r7 = rg & 7;

    xtg += (long)b * NPX * CIN;
    q2g += (long)b * NPX * KC;

    // ---------------- G1: h1 = relu(wp1 . xT + bp1), K=512 ----------------
    f32x4 a1[16];
    #pragma unroll
    for (int i = 0; i < 16; ++i) a1[i] = (f32x4){0.f, 0.f, 0.f, 0.f};

    for (int kt = 0; kt < 8; ++kt) {
        #pragma unroll
        for (int it = 0; it < 4; ++it) {      // WA: 2048 chunks
            int idx = it * 512 + tid;
            int row = idx >> 3, c = idx & 7;
            gload_lds16(wp1 + (long)row * CIN + (kt * 8 + (c ^ (row & 7))) * 8,
                        WA + (it * 512 + wid * 64) * 8);
        }
        #pragma unroll
        for (int it = 0; it < 2; ++it) {      // XB: 1024 chunks
            int idx = it * 512 + tid;
            int row = idx >> 3, c = idx & 7;
            gload_lds16(xtg + (long)(n0 + row) * CIN + (kt * 8 + (c ^ (row & 7))) * 8,
                        XB + (it * 512 + wid * 64) * 8);
        }
        __syncthreads();
        #pragma unroll
        for (int s = 0; s < 2; ++s) {
            const int cc = (4 * s + kg) ^ r7;       // 8-chunk rows
            short8 bx = *(const short8*)(XB + (wid * 16 + rg) * 64 + cc * 8);
            #pragma unroll
            for (int i = 0; i < 16; ++i) {
                short8 a = *(const short8*)(WA + (i * 16 + rg) * 64 + cc * 8);
                a1[i] = __builtin_amdgcn_mfma_f32_16x16x32_bf16(a, bx, a1[i], 0, 0, 0);
            }
        }
        __syncthreads();
    }

    // h1 -> LDS [128][256] (bias+relu, packed b64 writes, swizzled)
    #pragma unroll
    for (int i = 0; i < 16; ++i) {
        const int kcb = i * 16 + kg * 4;
        f32x4 bv = *(const f32x4*)(bp1 + kcb);
        float v0 = fmaxf(a1[i][0] + bv.x, 0.f), v1 = fmaxf(a1[i][1] + bv.y, 0.f);
        float v2 = fmaxf(a1[i][2] + bv.z, 0.f), v3 = fmaxf(a1[i][3] + bv.w, 0.f);
        uint2 pk;
        pk.x = (unsigned)f2bf(v0) | ((unsigned)f2bf(v1) << 16);
        pk.y = (unsigned)f2bf(v2) | ((unsigned)f2bf(v3) << 16);
        const int c = 2 * i + (kg >> 1);
        *(uint2*)(H1 + (wid * 16 + rg) * 256 + swz8(c, r7) * 8 + (kg & 1) * 4) = pk;
    }

    // ---------------- G2: q2 = relu(wp2 . h1 + bp2), K=256 ----------------
    f32x4 a2[16];
    #pragma unroll
    for (int i = 0; i < 16; ++i) a2[i] = (f32x4){0.f, 0.f, 0.f, 0.f};

    for (int S = 0; S < 8; ++S) {
        #pragma unroll
        for (int it = 0; it < 2; ++it) {      // W2: 1024 chunks [256][4]
            int idx = it * 512 + tid;
            int row = idx >> 2, c = idx & 3;
            gload_lds16(wp2 + (long)row * KC + (S * 4 + (c ^ (row & 3))) * 8,
                        W2 + (it * 512 + wid * 64) * 8);
        }
        __syncthreads();
        {
            const int cb = 4 * S + kg;
            short8 bh = *(const short8*)(H1 + (wid * 16 + rg) * 256 + swz8(cb, r7) * 8);
            #pragma unroll
            for (int i = 0; i < 16; ++i) {
                short8 a = *(const short8*)(W2 + (i * 16 + rg) * 32 + (kg ^ (rg & 3)) * 8);
                a2[i] = __builtin_amdgcn_mfma_f32_16x16x32_bf16(a, bh, a2[i], 0, 0, 0);
            }
        }
        __syncthreads();
    }

    // q2 -> global [n][256] bf16 (8B stores)
    #pragma unroll
    for (int i = 0; i < 16; ++i) {
        const int kcb = i * 16 + kg * 4;
        f32x4 bv = *(const f32x4*)(bp2 + kcb);
        float v0 = fmaxf(a2[i][0] + bv.x, 0.f), v1 = fmaxf(a2[i][1] + bv.y, 0.f);
        float v2 = fmaxf(a2[i][2] + bv.z, 0.f), v3 = fmaxf(a2[i][3] + bv.w, 0.f);
        uint2 pk;
        pk.x = (unsigned)f2bf(v0) | ((unsigned)f2bf(v1) << 16);
        pk.y = (unsigned)f2bf(v2) | ((unsigned)f2bf(v3) << 16);
        *(uint2*)(q2g + (long)(n0 + wid * 16 + rg) * KC + kcb) = pk;
    }
}

// ===========================================================================
// kernelB: sim = key.q2/16 -> softmax(kp<150) -> context = vT.P -> out =
// relu(w_u.context + b_u).  LDS 144KB phase-overlaid, 1 block/CU, 8 waves.
// ===========================================================================
__global__ __launch_bounds__(512, 2)
void attn_out_kernel(const u16* __restrict__ q2g, const u16* __restrict__ keyg,
                     const u16* __restrict__ vtg, const u16* __restrict__ wug,
                     const float* __restrict__ bu, float* __restrict__ out)
{
    __shared__ u16 sh[73728];          // 144 KB
    u16* Q  = sh;                      // [128][256] 64KB   (phase A)
    u16* KY = sh + 32768;              // [160][256] 80KB   (phase A)
    u16* P  = sh;                      // [128][192] 48KB   (phase B)
    u16* V  = sh + 24576;              // [256][192] 96KB   (phase B)
    u16* CX = sh;                      // [128][256] 64KB   (phase C)
    u16* WU = sh + 32768;              // 2x[512][4ch] 64KB (phase C)

    const int b  = blockIdx.z;
    const int n0 = blockIdx.x * 128;
    const int tid = threadIdx.x, lane = tid & 63, wid = tid >> 6;
    const int rg = lane & 15, kg = lane >> 4;
    const int r7 = rg & 7;

    q2g  += (long)b * NPX * KC;
    keyg += (long)b * 160 * KC;
    vtg  += (long)b * KC * KVP;
    out  += (long)b * CIN * NPX;

    // ---- stage q2 tile + key ----
    #pragma unroll
    for (int it = 0; it < 8; ++it) {          // Q: 4096 chunks
        int idx = it * 512 + tid;
        int row = idx >> 5, c = idx & 31;
        gload_lds16(q2g + (long)(n0 + row) * KC + swz8(c, row & 7) * 8,
                    Q + (it * 512 + wid * 64) * 8);
    }
    #pragma unroll
    for (int it = 0; it < 10; ++it) {         // KY: 5120 chunks
        int idx = it * 512 + tid;
        int row = idx >> 5, c = idx & 31;
        gload_lds16(keyg + (long)row * KC + swz8(c, row & 7) * 8,
                    KY + (it * 512 + wid * 64) * 8);
    }
    __syncthreads();

    // ---- G3: sim[kp][n], M=160 (10 frags), K=256 ----
    f32x4 s1[10];
    #pragma unroll
    for (int i = 0; i < 10; ++i) s1[i] = (f32x4){0.f, 0.f, 0.f, 0.f};
    for (int s = 0; s < 8; ++s) {
        const int cc = swz8(4 * s + kg, r7);
        short8 bq = *(const short8*)(Q + (wid * 16 + rg) * 256 + cc * 8);
        #pragma unroll
        for (int i = 0; i < 10; ++i) {
            short8 a = *(const short8*)(KY + (i * 16 + rg) * 256 + cc * 8);
            s1[i] = __builtin_amdgcn_mfma_f32_16x16x32_bf16(a, bq, s1[i], 0, 0, 0);
        }
    }

    // ---- softmax over kp (mask kp>=150), cross-kg shfl reduce ----
    float mx = -3.0e38f;
    #pragma unroll
    for (int i = 0; i < 9; ++i)
        #pragma unroll
        for (int r = 0; r < 4; ++r) mx = fmaxf(mx, s1[i][r]);
    #pragma unroll
    for (int r = 0; r < 4; ++r) if (kg * 4 + r < 6) mx = fmaxf(mx, s1[9][r]);
    mx = fmaxf(mx, __shfl_xor(mx, 16));
    mx = fmaxf(mx, __shfl_xor(mx, 32));
    float l = 0.f;
    #pragma unroll
    for (int i = 0; i < 10; ++i)
        #pragma unroll
        for (int r = 0; r < 4; ++r) {
            const bool valid = (i < 9) || (kg * 4 + r < 6);
            float e = valid ? __expf((s1[i][r] - mx) * 0.0625f) : 0.f;
            s1[i][r] = e; l += e;
        }
    l += __shfl_xor(l, 16);
    l += __shfl_xor(l, 32);
    const float inv = 1.f / l;

    __syncthreads();   // all waves done with Q/KY before overlay

    // ---- P -> LDS [128][192] normalized bf16; zero chunks 20..23 ----
    #pragma unroll
    for (int i = 0; i < 10; ++i) {
        uint2 pk;
        pk.x = (unsigned)f2bf(s1[i][0] * inv) | ((unsigned)f2bf(s1[i][1] * inv) << 16);
        pk.y = (unsigned)f2bf(s1[i][2] * inv) | ((unsigned)f2bf(s1[i][3] * inv) << 16);
        const int c = 2 * i + (kg >> 1);
        *(uint2*)(P + (wid * 16 + rg) * KVP + swz8(c, r7) * 8 + (kg & 1) * 4) = pk;
    }
    {
        const int row = tid >> 2, c = 20 + (tid & 3);
        u32x4 z = (u32x4){0u, 0u, 0u, 0u};
        *(u32x4*)(P + row * KVP + swz8(c, row & 7) * 8) = z;
    }
    // ---- stage vT [256][192] (24 chunks/row) ----
    #pragma unroll
    for (int it = 0; it < 12; ++it) {         // 6144 chunks
        int idx = it * 512 + tid;
        int row = idx / 24, c = idx - row * 24;
        gload_lds16(vtg + (long)row * KVP + swz8(c, row & 7) * 8,
                    V + (it * 512 + wid * 64) * 8);
    }
    __syncthreads();

    // ---- G4: context[kc][n] = vT . P, M=256 (16 frags), K=160 ----
    f32x4 s2[16];
    #pragma unroll
    for (int i = 0; i < 16; ++i) s2[i] = (f32x4){0.f, 0.f, 0.f, 0.f};
    for (int s = 0; s < 5; ++s) {
        const int cc = swz8(4 * s + kg, r7);
        short8 bp = *(const short8*)(P + (wid * 16 + rg) * KVP + cc * 8);
        #pragma unroll
        for (int i = 0; i < 16; ++i) {
            short8 a = *(const short8*)(V + (i * 16 + rg) * KVP + cc * 8);
            s2[i] = __builtin_amdgcn_mfma_f32_16x16x32_bf16(a, bp, s2[i], 0, 0, 0);
        }
    }
    __syncthreads();   // all waves done with P/V before overlay

    // ---- context -> LDS [128][256] bf16 + stage first w_u tile ----
    #pragma unroll
    for (int i = 0; i < 16; ++i) {
        uint2 pk;
        pk.x = (unsigned)f2bf(s2[i][0]) | ((unsigned)f2bf(s2[i][1]) << 16);
        pk.y = (unsigned)f2bf(s2[i][2]) | ((unsigned)f2bf(s2[i][3]) << 16);
        const int c = 2 * i + (kg >> 1);
        *(uint2*)(CX + (wid * 16 + rg) * 256 + swz8(c, r7) * 8 + (kg & 1) * 4) = pk;
    }
    auto STAGEW = [&](int buf, int S) {
        #pragma unroll
        for (int it = 0; it < 4; ++it) {      // 2048 chunks [512][4]
            int idx = it * 512 + tid;
            int row = idx >> 2, c = idx & 3;
            gload_lds16(wug + (long)row * KC + (S * 4 + (c ^ (row & 3))) * 8,
                        WU + buf * 16384 + (it * 512 + wid * 64) * 8);
        }
    };
    STAGEW(0, 0);
    __syncthreads();

    // ---- G5: out = relu(w_u . context + b_u), M=512 (32 frags), K=256 ----
    f32x4 s3[32];
    #pragma unroll
    for (int i = 0; i < 32; ++i) s3[i] = (f32x4){0.f, 0.f, 0.f, 0.f};
    for (int S = 0; S < 8; ++S) {
        if (S < 7) STAGEW((S + 1) & 1, S + 1);
        const u16* W = WU + (S & 1) * 16384;
        const int cxc = swz8(4 * S + kg, r7);
        short8 bc = *(const short8*)(CX + (wid * 16 + rg) * 256 + cxc * 8);
        const int wc = (kg ^ (rg & 3)) * 8;
        #pragma unroll
        for (int i = 0; i < 32; ++i) {
            short8 a = *(const short8*)(W + (i * 16 + rg) * 32 + wc);
            s3[i] = __builtin_amdgcn_mfma_f32_16x16x32_bf16(a, bc, s3[i], 0, 0, 0);
        }
        __syncthreads();
    }

    // ---- epilogue: out[c][n] fp32, coalesced across rg ----
    const int ncol = n0 + wid * 16 + rg;
    #pragma unroll
    for (int i = 0; i < 32; ++i) {
        const int c4 = i * 16 + kg * 4;
        f32x4 bv = *(const f32x4*)(bu + c4);
        out[(long)(c4 + 0) * NPX + ncol] = fmaxf(s3[i][0] + bv.x, 0.f);
        out[(long)(c4 + 1) * NPX + ncol] = fmaxf(s3[i][1] + bv.y, 0.f);
        out[(long)(c4 + 2) * NPX + ncol] = fmaxf(s3[i][2] + bv.z, 0.f);
        out[(long)(c4 + 3) * NPX + ncol] = fmaxf(s3[i][3] + bv.w, 0.f);
    }
}

// ---------------------------------------------------------------------------
// transpose: x [b][512][16384] fp32 -> xT [b][16384][512] bf16. 64x64 tiles.
// ---------------------------------------------------------------------------
__global__ __launch_bounds__(256)
void transpose_x(const float* __restrict__ x, u16* __restrict__ xT)
{
    __shared__ u16 t[64][73];
    const int b  = blockIdx.z;
    const int n0 = blockIdx.x * 64, c0 = blockIdx.y * 64;
    const int tid = threadIdx.x;
    const int ln = tid & 63, cq = tid >> 6;
    const float* xp = x + ((long)b * CIN + c0) * NPX + n0 + ln;
    #pragma unroll
    for (int cc = 0; cc < 16; ++cc) {
        const int c = cc * 4 + cq;
        t[c][ln] = f2bf(xp[(long)c * NPX]);
    }
    __syncthreads();
    const int n = tid >> 2, ch = (tid & 3) * 16;
    u16 tmp[16];
    #pragma unroll
    for (int j = 0; j < 16; ++j) tmp[j] = t[ch + j][n];
    u32x4 v0, v1;
    v0.x = tmp[0] | ((unsigned)tmp[1] << 16);  v0.y = tmp[2] | ((unsigned)tmp[3] << 16);
    v0.z = tmp[4] | ((unsigned)tmp[5] << 16);  v0.w = tmp[6] | ((unsigned)tmp[7] << 16);
    v1.x = tmp[8] | ((unsigned)tmp[9] << 16);  v1.y = tmp[10] | ((unsigned)tmp[11] << 16);
    v1.z = tmp[12] | ((unsigned)tmp[13] << 16); v1.w = tmp[14] | ((unsigned)tmp[15] << 16);
    u16* op = xT + ((long)b * NPX + n0 + n) * CIN + c0 + ch;
    *(u32x4*)op = v0;
    *(u32x4*)(op + 8) = v1;
}

// ---------------------------------------------------------------------------
// kv1: hidden[b][kc][kp](fp32, stride 160) = relu(w_o1 . proxy + b_o1)
//      vT[b][kc][kp](bf16, stride 192, pad 0) = relu(w_d . proxy + b_d)
// ---------------------------------------------------------------------------
__global__ void kv1_kernel(const float* __restrict__ proxy,
                           const float* __restrict__ w_o1, const float* __restrict__ b_o1,
                           const float* __restrict__ w_d,  const float* __restrict__ b_d,
                           float* __restrict__ hidden, u16* __restrict__ vT)
{
    const int kc = blockIdx.x;
    const int b  = blockIdx.y;
    const int kp = threadIdx.x;   // 0..191
    float ah = 0.f, av = 0.f;
    if (kp < KP) {
        const float* px = proxy + (long)b * CIN * KP + kp;
        const float* w1 = w_o1 + (long)kc * CIN;
        const float* wd = w_d  + (long)kc * CIN;
        for (int c = 0; c < CIN; ++c) {
            float p = px[(long)c * KP];
            ah += w1[c] * p;
            av += wd[c] * p;
        }
        ah = fmaxf(ah + b_o1[kc], 0.f);
        av = fmaxf(av + b_d[kc], 0.f);
    }
    if (kp < 160) hidden[((long)b * KC + kc) * 160 + kp] = ah;
    vT[((long)b * KC + kc) * KVP + kp] = f2bf(av);
}

// kv2: keyT[b][kp][kc] (160 rows, kp>=150 zero) = relu(w_o2 . hidden + b_o2)
__global__ void kv2_kernel(const float* __restrict__ hidden,
                           const float* __restrict__ w_o2, const float* __restrict__ b_o2,
                           u16* __restrict__ keyT)
{
    const int kp = blockIdx.x;   // 0..159
    const int b  = blockIdx.y;
    const int kc = threadIdx.x;  // 0..255
    long o = ((long)b * 160 + kp) * KC + kc;
    if (kp >= KP) { keyT[o] = 0; return; }
    const float* w = w_o2 + (long)kc * KC;
    const float* h = hidden + (long)b * KC * 160 + kp;
    float acc = 0.f;
    for (int c = 0; c < KC; ++c)
        acc += w[c] * h[(long)c * 160];
    keyT[o] = f2bf(fmaxf(acc + b_o2[kc], 0.f));
}

// fp32 -> bf16 conversion of the three shared weight matrices
__global__ void prep_w(const float* __restrict__ w1, const float* __restrict__ w2,
                       const float* __restrict__ w3,
                       u16* __restrict__ o1, u16* __restrict__ o2, u16* __restrict__ o3)
{
    int i = blockIdx.x * 256 + threadIdx.x;
    if (i < KC * CIN) o1[i] = f2bf(w1[i]);
    if (i < KC * KC)  o2[i] = f2bf(w2[i]);
    if (i < CIN * KC) o3[i] = f2bf(w3[i]);
}

extern "C" void kernel_launch(void* const* d_in, const int* in_sizes, int n_in,
                              void* d_out, int out_size, void* d_ws, size_t ws_size,
                              hipStream_t stream)
{
    const float* x     = (const float*)d_in[0];
    const float* proxy = (const float*)d_in[1];
    const float* w_p1  = (const float*)d_in[2];
    const float* b_p1  = (const float*)d_in[3];
    const float* w_p2  = (const float*)d_in[4];
    const float* b_p2  = (const float*)d_in[5];
    const float* w_o1  = (const float*)d_in[6];
    const float* b_o1  = (const float*)d_in[7];
    const float* w_o2  = (const float*)d_in[8];
    const float* b_o2  = (const float*)d_in[9];
    const float* w_d   = (const float*)d_in[10];
    const float* b_d   = (const float*)d_in[11];
    const float* w_u   = (const float*)d_in[12];
    const float* b_u   = (const float*)d_in[13];
    float* out = (float*)d_out;
    (void)in_sizes; (void)n_in; (void)out_size; (void)ws_size;

    char* ws = (char*)d_ws;
    size_t off = 0;
    auto alloc = [&](size_t bytes) { size_t o = off; off += (bytes + 255) & ~(size_t)255; return o; };

    u16*   wb_p1  = (u16*)  (ws + alloc((size_t)KC * CIN * 2));
    u16*   wb_p2  = (u16*)  (ws + alloc((size_t)KC * KC * 2));
    u16*   wb_u   = (u16*)  (ws + alloc((size_t)CIN * KC * 2));
    u16*   keyT   = (u16*)  (ws + alloc((size_t)NB * 160 * KC * 2));
    u16*   vT     = (u16*)  (ws + alloc((size_t)NB * KC * KVP * 2));
    float* hidden = (float*)(ws + alloc((size_t)NB * KC * 160 * 4));
    u16*   xT     = (u16*)  (ws + alloc((size_t)NB * NPX * CIN * 2)); // 67 MB
    u16*   q2     = (u16*)  (ws + alloc((size_t)NB * NPX * KC * 2));  // 33.5 MB

    prep_w<<<512, 256, 0, stream>>>(w_p1, w_p2, w_u, wb_p1, wb_p2, wb_u);
    transpose_x<<<dim3(NPX / 64, CIN / 64, NB), 256, 0, stream>>>(x, xT);
    kv1_kernel<<<dim3(KC, NB), KVP, 0, stream>>>(proxy, w_o1, b_o1, w_d, b_d, hidden, vT);
    kv2_kernel<<<dim3(160, NB), 256, 0, stream>>>(hidden, w_o2, b_o2, keyT);

    g12_kernel<<<dim3(NPX / 128, 1, NB), 512, 0, stream>>>(
        wb_p1, xT, wb_p2, b_p1, b_p2, q2);
    attn_out_kernel<<<dim3(NPX / 128, 1, NB), 512, 0, stream>>>(
        q2, keyT, vT, wb_u, b_u, out);
}

// Round 4
// 159.354 us; speedup vs baseline: 2.1590x; 1.4168x over previous
//
#include <hip/hip_runtime.h>
#include <hip/hip_bf16.h>

#define NB   4      // batch
#define CIN  512    // in channels
#define NPX  16384  // H*W
#define KC   256    // key channels
#define KP   150    // proxy regions
#define KVP  192    // kp padded for vT/P rows (24 chunks)

typedef __attribute__((ext_vector_type(8))) short short8;
typedef __attribute__((ext_vector_type(4))) float f32x4;
typedef __attribute__((ext_vector_type(4))) unsigned int u32x4;
typedef unsigned short u16;

__device__ __forceinline__ u16 f2bf(float f) {
    unsigned int u = __float_as_uint(f);
    return (u16)((u + 0x7FFFu + ((u >> 16) & 1u)) >> 16);
}
__device__ __forceinline__ unsigned pk2(float a, float b) {
    return (unsigned)f2bf(a) | ((unsigned)f2bf(b) << 16);
}
__device__ __forceinline__ void gload_lds16(const void* g, void* l) {
    __builtin_amdgcn_global_load_lds(
        (const __attribute__((address_space(1))) unsigned int*)g,
        (__attribute__((address_space(3))) unsigned int*)l,
        16, 0, 0);
}
__device__ __forceinline__ int swz8(int c, int r7) { return (c & ~7) | ((c & 7) ^ r7); }

// ===========================================================================
// Fused: x(fp32) -> G1 -> G2 -> G3 -> softmax -> G4 -> G5 -> out(fp32)
// per 128-pixel tile. 512 thr = 8 waves = 4 m-groups x 2 n-groups.
// LDS 144KB phase-overlaid (u16 offsets):
//   phase1: WA dbuf [0,32768) + XB dbuf [32768,49152)
//   phase2: H1 [0,32768) + W2 dbuf [32768,49152); Q [40960,73728) written after
//   phase3: KY1 [0,32768) + KY2 [32768,40960) + Q
//   phase4: P [0,24576) + V [24576,73728)
//   phase5: CX [0,32768) + WU dbuf [32768,65536)
// ===========================================================================
__global__ __launch_bounds__(512, 2)
void fused_kernel(const u16* __restrict__ wp1, const float* __restrict__ xg,
                  const u16* __restrict__ wp2, const float* __restrict__ bp1,
                  const float* __restrict__ bp2, const u16* __restrict__ keyg,
                  const u16* __restrict__ vtg, const u16* __restrict__ wug,
                  const float* __restrict__ bu, float* __restrict__ outg)
{
    __shared__ u16 sh[73728];   // 144 KB

    const int b  = blockIdx.z;
    const int n0 = blockIdx.x * 128;
    const int tid = threadIdx.x, lane = tid & 63, wid = tid >> 6;
    const int rg = lane & 15, kg = lane >> 4;
    const int r7 = rg & 7;
    const int mg = wid >> 1, ng = wid & 1;    // 4 x 2 wave grid

    const float* xb = xg + (long)b * CIN * NPX;
    const u16* kyb  = keyg + (long)b * 160 * KC;
    const u16* vb   = vtg + (long)b * KC * KVP;
    float* ob       = outg + (long)b * CIN * NPX;

    // ------------------------- phase 1: G1 (K=512) -------------------------
    // x staging ids: thread covers n = tid&127, k-block (tid>>7)*16..+16
    const int sxn = tid & 127, sxk = tid >> 7;
    const float* xsrc = xb + (long)(sxk * 16) * NPX + n0 + sxn;

    auto STAGE_WA = [&](int buf, int kt) {
        #pragma unroll
        for (int it = 0; it < 4; ++it) {
            int idx = it * 512 + tid;
            int row = idx >> 3, c = idx & 7;
            gload_lds16(wp1 + (long)row * CIN + (kt * 8 + (c ^ (row & 7))) * 8,
                        sh + buf * 16384 + (it * 512 + wid * 64) * 8);
        }
    };
    float xr[16];
    auto LOADX = [&](int kt) {
        #pragma unroll
        for (int e = 0; e < 16; ++e)
            xr[e] = xsrc[(long)(kt * 64 + e) * NPX];
    };
    auto WRITE_XB = [&](int buf) {
        #pragma unroll
        for (int h = 0; h < 2; ++h) {
            u32x4 v;
            v.x = pk2(xr[h * 8 + 0], xr[h * 8 + 1]);
            v.y = pk2(xr[h * 8 + 2], xr[h * 8 + 3]);
            v.z = pk2(xr[h * 8 + 4], xr[h * 8 + 5]);
            v.w = pk2(xr[h * 8 + 6], xr[h * 8 + 7]);
            int p = (sxk * 2 + h) ^ (sxn & 7);
            *(u32x4*)(sh + 32768 + buf * 8192 + sxn * 64 + p * 8) = v;
        }
    };

    STAGE_WA(0, 0); LOADX(0); WRITE_XB(0);
    __syncthreads();

    f32x4 acc[4][4];
    #pragma unroll
    for (int i = 0; i < 4; ++i)
        #pragma unroll
        for (int j = 0; j < 4; ++j) acc[i][j] = (f32x4){0.f, 0.f, 0.f, 0.f};

    for (int kt = 0; kt < 8; ++kt) {
        const int buf = kt & 1;
        if (kt < 7) { STAGE_WA(buf ^ 1, kt + 1); LOADX(kt + 1); }
        #pragma unroll
        for (int s = 0; s < 2; ++s) {
            const int cc = (4 * s + kg) ^ r7;
            short8 a[4], bb[4];
            #pragma unroll
            for (int i = 0; i < 4; ++i)
                a[i] = *(const short8*)(sh + buf * 16384 + (mg * 64 + i * 16 + rg) * 64 + cc * 8);
            #pragma unroll
            for (int j = 0; j < 4; ++j)
                bb[j] = *(const short8*)(sh + 32768 + buf * 8192 + (ng * 64 + j * 16 + rg) * 64 + cc * 8);
            #pragma unroll
            for (int i = 0; i < 4; ++i)
                #pragma unroll
                for (int j = 0; j < 4; ++j)
                    acc[i][j] = __builtin_amdgcn_mfma_f32_16x16x32_bf16(a[i], bb[j], acc[i][j], 0, 0, 0);
        }
        if (kt < 7) WRITE_XB(buf ^ 1);
        __syncthreads();
    }

    // h1 -> LDS H1[0,32768): [n][256] bf16 swizzled, bias+relu
    #pragma unroll
    for (int i = 0; i < 4; ++i) {
        const int kc = mg * 64 + i * 16 + kg * 4;
        const f32x4 bv = *(const f32x4*)(bp1 + kc);
        const int c = mg * 8 + 2 * i + (kg >> 1);
        #pragma unroll
        for (int j = 0; j < 4; ++j) {
            const int n = ng * 64 + j * 16 + rg;
            uint2 pk;
            pk.x = pk2(fmaxf(acc[i][j][0] + bv.x, 0.f), fmaxf(acc[i][j][1] + bv.y, 0.f));
            pk.y = pk2(fmaxf(acc[i][j][2] + bv.z, 0.f), fmaxf(acc[i][j][3] + bv.w, 0.f));
            *(uint2*)(sh + n * 256 + swz8(c, r7) * 8 + (kg & 1) * 4) = pk;
        }
    }

    // ------------------------- phase 2: G2 (K=256) -------------------------
    auto STAGE_W2 = [&](int buf, int S) {
        #pragma unroll
        for (int it = 0; it < 2; ++it) {
            int idx = it * 512 + tid;
            int row = idx >> 2, c = idx & 3;
            gload_lds16(wp2 + (long)row * KC + (S * 4 + (c ^ (row & 3))) * 8,
                        sh + 32768 + buf * 8192 + (it * 512 + wid * 64) * 8);
        }
    };
    STAGE_W2(0, 0);
    __syncthreads();

    f32x4 acc2[4][4];
    #pragma unroll
    for (int i = 0; i < 4; ++i)
        #pragma unroll
        for (int j = 0; j < 4; ++j) acc2[i][j] = (f32x4){0.f, 0.f, 0.f, 0.f};

    for (int S = 0; S < 8; ++S) {
        const int buf = S & 1;
        if (S < 7) STAGE_W2(buf ^ 1, S + 1);
        short8 a[4], bb[4];
        #pragma unroll
        for (int i = 0; i < 4; ++i)
            a[i] = *(const short8*)(sh + 32768 + buf * 8192 + (mg * 64 + i * 16 + rg) * 32 + (kg ^ (rg & 3)) * 8);
        #pragma unroll
        for (int j = 0; j < 4; ++j)
            bb[j] = *(const short8*)(sh + (ng * 64 + j * 16 + rg) * 256 + swz8(S * 4 + kg, r7) * 8);
        #pragma unroll
        for (int i = 0; i < 4; ++i)
            #pragma unroll
            for (int j = 0; j < 4; ++j)
                acc2[i][j] = __builtin_amdgcn_mfma_f32_16x16x32_bf16(a[i], bb[j], acc2[i][j], 0, 0, 0);
        __syncthreads();
    }

    // q2 -> Q [40960,73728): [n][256] bf16 swizzled, bias+relu
    #pragma unroll
    for (int i = 0; i < 4; ++i) {
        const int kc = mg * 64 + i * 16 + kg * 4;
        const f32x4 bv = *(const f32x4*)(bp2 + kc);
        const int c = mg * 8 + 2 * i + (kg >> 1);
        #pragma unroll
        for (int j = 0; j < 4; ++j) {
            const int n = ng * 64 + j * 16 + rg;
            uint2 pk;
            pk.x = pk2(fmaxf(acc2[i][j][0] + bv.x, 0.f), fmaxf(acc2[i][j][1] + bv.y, 0.f));
            pk.y = pk2(fmaxf(acc2[i][j][2] + bv.z, 0.f), fmaxf(acc2[i][j][3] + bv.w, 0.f));
            *(uint2*)(sh + 40960 + n * 256 + swz8(c, r7) * 8 + (kg & 1) * 4) = pk;
        }
    }
    // stage KY: rows 0..127 -> [0,32768), rows 128..159 -> [32768,40960)
    #pragma unroll
    for (int it = 0; it < 8; ++it) {
        int idx = it * 512 + tid;
        int row = idx >> 5, c = idx & 31;
        gload_lds16(kyb + (long)row * KC + swz8(c, row & 7) * 8,
                    sh + (it * 512 + wid * 64) * 8);
    }
    #pragma unroll
    for (int it = 0; it < 2; ++it) {
        int idx = it * 512 + tid;
        int row = 128 + (idx >> 5), c = idx & 31;
        gload_lds16(kyb + (long)row * KC + swz8(c, row & 7) * 8,
                    sh + 32768 + (it * 512 + wid * 64) * 8);
    }
    __syncthreads();

    // ------------------- phase 3: G3 (old mapping) + softmax ----------------
    // wave wid owns pixels n = wid*16 + rg; A = KY (10 frags)
    f32x4 s1[10];
    #pragma unroll
    for (int i = 0; i < 10; ++i) s1[i] = (f32x4){0.f, 0.f, 0.f, 0.f};
    for (int s = 0; s < 8; ++s) {
        const int cc = swz8(4 * s + kg, r7);
        short8 bq = *(const short8*)(sh + 40960 + (wid * 16 + rg) * 256 + cc * 8);
        #pragma unroll
        for (int i = 0; i < 10; ++i) {
            const u16* krow = (i < 8) ? (sh + (i * 16 + rg) * 256)
                                      : (sh + 32768 + ((i - 8) * 16 + rg) * 256);
            short8 a = *(const short8*)(krow + cc * 8);
            s1[i] = __builtin_amdgcn_mfma_f32_16x16x32_bf16(a, bq, s1[i], 0, 0, 0);
        }
    }
    // softmax over kp (mask kp>=150), cross-kg shfl reduce (verified r2/r3)
    float mx = -3.0e38f;
    #pragma unroll
    for (int i = 0; i < 9; ++i)
        #pragma unroll
        for (int r = 0; r < 4; ++r) mx = fmaxf(mx, s1[i][r]);
    #pragma unroll
    for (int r = 0; r < 4; ++r) if (kg * 4 + r < 6) mx = fmaxf(mx, s1[9][r]);
    mx = fmaxf(mx, __shfl_xor(mx, 16));
    mx = fmaxf(mx, __shfl_xor(mx, 32));
    float l = 0.f;
    #pragma unroll
    for (int i = 0; i < 10; ++i)
        #pragma unroll
        for (int r = 0; r < 4; ++r) {
            const bool valid = (i < 9) || (kg * 4 + r < 6);
            float e = valid ? __expf((s1[i][r] - mx) * 0.0625f) : 0.f;
            s1[i][r] = e; l += e;
        }
    l += __shfl_xor(l, 16);
    l += __shfl_xor(l, 32);
    const float inv = 1.f / l;

    __syncthreads();   // all waves done reading Q/KY

    // P -> [0,24576): [n][192] normalized bf16 swizzled
    #pragma unroll
    for (int i = 0; i < 10; ++i) {
        uint2 pk;
        pk.x = pk2(s1[i][0] * inv, s1[i][1] * inv);
        pk.y = pk2(s1[i][2] * inv, s1[i][3] * inv);
        const int c = 2 * i + (kg >> 1);
        *(uint2*)(sh + (wid * 16 + rg) * KVP + swz8(c, r7) * 8 + (kg & 1) * 4) = pk;
    }
    // stage V [24576,73728): [256][192]
    #pragma unroll
    for (int it = 0; it < 12; ++it) {
        int idx = it * 512 + tid;
        int row = idx / 24, c = idx - row * 24;
        gload_lds16(vb + (long)row * KVP + swz8(c, row & 7) * 8,
                    sh + 24576 + (it * 512 + wid * 64) * 8);
    }
    __syncthreads();

    // ------------------------- phase 4: G4 (K=160) -------------------------
    f32x4 acc4[4][4];
    #pragma unroll
    for (int i = 0; i < 4; ++i)
        #pragma unroll
        for (int j = 0; j < 4; ++j) acc4[i][j] = (f32x4){0.f, 0.f, 0.f, 0.f};
    for (int s = 0; s < 5; ++s) {
        const int cc = swz8(4 * s + kg, r7);
        short8 a[4], bb[4];
        #pragma unroll
        for (int i = 0; i < 4; ++i)
            a[i] = *(const short8*)(sh + 24576 + (mg * 64 + i * 16 + rg) * KVP + cc * 8);
        #pragma unroll
        for (int j = 0; j < 4; ++j)
            bb[j] = *(const short8*)(sh + (ng * 64 + j * 16 + rg) * KVP + cc * 8);
        #pragma unroll
        for (int i = 0; i < 4; ++i)
            #pragma unroll
            for (int j = 0; j < 4; ++j)
                acc4[i][j] = __builtin_amdgcn_mfma_f32_16x16x32_bf16(a[i], bb[j], acc4[i][j], 0, 0, 0);
    }
    __syncthreads();   // all waves done reading P/V

    // context -> CX [0,32768): [n][256] bf16 swizzled
    #pragma unroll
    for (int i = 0; i < 4; ++i) {
        const int c = mg * 8 + 2 * i + (kg >> 1);
        #pragma unroll
        for (int j = 0; j < 4; ++j) {
            const int n = ng * 64 + j * 16 + rg;
            uint2 pk;
            pk.x = pk2(acc4[i][j][0], acc4[i][j][1]);
            pk.y = pk2(acc4[i][j][2], acc4[i][j][3]);
            *(uint2*)(sh + n * 256 + swz8(c, r7) * 8 + (kg & 1) * 4) = pk;
        }
    }
    auto STAGE_WU = [&](int buf, int S) {
        #pragma unroll
        for (int it = 0; it < 4; ++it) {
            int idx = it * 512 + tid;
            int row = idx >> 2, c = idx & 3;
            gload_lds16(wug + (long)row * KC + (S * 4 + (c ^ (row & 3))) * 8,
                        sh + 32768 + buf * 16384 + (it * 512 + wid * 64) * 8);
        }
    };
    STAGE_WU(0, 0);
    __syncthreads();

    // ------------------------- phase 5: G5 (K=256) -------------------------
    f32x4 acc5[8][4];
    #pragma unroll
    for (int i = 0; i < 8; ++i)
        #pragma unroll
        for (int j = 0; j < 4; ++j) acc5[i][j] = (f32x4){0.f, 0.f, 0.f, 0.f};
    for (int S = 0; S < 8; ++S) {
        const int buf = S & 1;
        if (S < 7) STAGE_WU(buf ^ 1, S + 1);
        short8 bb[4];
        #pragma unroll
        for (int j = 0; j < 4; ++j)
            bb[j] = *(const short8*)(sh + (ng * 64 + j * 16 + rg) * 256 + swz8(S * 4 + kg, r7) * 8);
        #pragma unroll
        for (int i = 0; i < 8; ++i) {
            short8 a = *(const short8*)(sh + 32768 + buf * 16384 + (mg * 128 + i * 16 + rg) * 32 + (kg ^ (rg & 3)) * 8);
            #pragma unroll
            for (int j = 0; j < 4; ++j)
                acc5[i][j] = __builtin_amdgcn_mfma_f32_16x16x32_bf16(a, bb[j], acc5[i][j], 0, 0, 0);
        }
        __syncthreads();
    }

    // epilogue: out[c][n] fp32 (+bias, relu), coalesced across rg
    #pragma unroll
    for (int i = 0; i < 8; ++i) {
        const int c4 = mg * 128 + i * 16 + kg * 4;
        const f32x4 bv = *(const f32x4*)(bu + c4);
        #pragma unroll
        for (int j = 0; j < 4; ++j) {
            const int n = n0 + ng * 64 + j * 16 + rg;
            ob[(long)(c4 + 0) * NPX + n] = fmaxf(acc5[i][j][0] + bv.x, 0.f);
            ob[(long)(c4 + 1) * NPX + n] = fmaxf(acc5[i][j][1] + bv.y, 0.f);
            ob[(long)(c4 + 2) * NPX + n] = fmaxf(acc5[i][j][2] + bv.z, 0.f);
            ob[(long)(c4 + 3) * NPX + n] = fmaxf(acc5[i][j][3] + bv.w, 0.f);
        }
    }
}

// ---------------------------------------------------------------------------
// kv1: hidden[b][kc][kp](fp32, stride 160) = relu(w_o1 . proxy + b_o1)
//      vT[b][kc][kp](bf16, stride 192, pad 0) = relu(w_d . proxy + b_d)
// ---------------------------------------------------------------------------
__global__ void kv1_kernel(const float* __restrict__ proxy,
                           const float* __restrict__ w_o1, const float* __restrict__ b_o1,
                           const float* __restrict__ w_d,  const float* __restrict__ b_d,
                           float* __restrict__ hidden, u16* __restrict__ vT)
{
    const int kc = blockIdx.x;
    const int b  = blockIdx.y;
    const int kp = threadIdx.x;   // 0..191
    float ah = 0.f, av = 0.f;
    if (kp < KP) {
        const float* px = proxy + (long)b * CIN * KP + kp;
        const float* w1 = w_o1 + (long)kc * CIN;
        const float* wd = w_d  + (long)kc * CIN;
        for (int c = 0; c < CIN; ++c) {
            float p = px[(long)c * KP];
            ah += w1[c] * p;
            av += wd[c] * p;
        }
        ah = fmaxf(ah + b_o1[kc], 0.f);
        av = fmaxf(av + b_d[kc], 0.f);
    }
    if (kp < 160) hidden[((long)b * KC + kc) * 160 + kp] = ah;
    vT[((long)b * KC + kc) * KVP + kp] = f2bf(av);
}

// kv2: keyT[b][kp][kc] (160 rows, kp>=150 zero) = relu(w_o2 . hidden + b_o2)
__global__ void kv2_kernel(const float* __restrict__ hidden,
                           const float* __restrict__ w_o2, const float* __restrict__ b_o2,
                           u16* __restrict__ keyT)
{
    const int kp = blockIdx.x;   // 0..159
    const int b  = blockIdx.y;
    const int kc = threadIdx.x;  // 0..255
    long o = ((long)b * 160 + kp) * KC + kc;
    if (kp >= KP) { keyT[o] = 0; return; }
    const float* w = w_o2 + (long)kc * KC;
    const float* h = hidden + (long)b * KC * 160 + kp;
    float acc = 0.f;
    for (int c = 0; c < KC; ++c)
        acc += w[c] * h[(long)c * 160];
    keyT[o] = f2bf(fmaxf(acc + b_o2[kc], 0.f));
}

// fp32 -> bf16 conversion of the three shared weight matrices
__global__ void prep_w(const float* __restrict__ w1, const float* __restrict__ w2,
                       const float* __restrict__ w3,
                       u16* __restrict__ o1, u16* __restrict__ o2, u16* __restrict__ o3)
{
    int i = blockIdx.x * 256 + threadIdx.x;
    if (i < KC * CIN) o1[i] = f2bf(w1[i]);
    if (i < KC * KC)  o2[i] = f2bf(w2[i]);
    if (i < CIN * KC) o3[i] = f2bf(w3[i]);
}

extern "C" void kernel_launch(void* const* d_in, const int* in_sizes, int n_in,
                              void* d_out, int out_size, void* d_ws, size_t ws_size,
                              hipStream_t stream)
{
    const float* x     = (const float*)d_in[0];
    const float* proxy = (const float*)d_in[1];
    const float* w_p1  = (const float*)d_in[2];
    const float* b_p1  = (const float*)d_in[3];
    const float* w_p2  = (const float*)d_in[4];
    const float* b_p2  = (const float*)d_in[5];
    const float* w_o1  = (const float*)d_in[6];
    const float* b_o1  = (const float*)d_in[7];
    const float* w_o2  = (const float*)d_in[8];
    const float* b_o2  = (const float*)d_in[9];
    const float* w_d   = (const float*)d_in[10];
    const float* b_d   = (const float*)d_in[11];
    const float* w_u   = (const float*)d_in[12];
    const float* b_u   = (const float*)d_in[13];
    float* out = (float*)d_out;
    (void)in_sizes; (void)n_in; (void)out_size; (void)ws_size;

    char* ws = (char*)d_ws;
    size_t off = 0;
    auto alloc = [&](size_t bytes) { size_t o = off; off += (bytes + 255) & ~(size_t)255; return o; };

    u16*   wb_p1  = (u16*)  (ws + alloc((size_t)KC * CIN * 2));
    u16*   wb_p2  = (u16*)  (ws + alloc((size_t)KC * KC * 2));
    u16*   wb_u   = (u16*)  (ws + alloc((size_t)CIN * KC * 2));
    u16*   keyT   = (u16*)  (ws + alloc((size_t)NB * 160 * KC * 2));
    u16*   vT     = (u16*)  (ws + alloc((size_t)NB * KC * KVP * 2));
    float* hidden = (float*)(ws + alloc((size_t)NB * KC * 160 * 4));

    prep_w<<<512, 256, 0, stream>>>(w_p1, w_p2, w_u, wb_p1, wb_p2, wb_u);
    kv1_kernel<<<dim3(KC, NB), KVP, 0, stream>>>(proxy, w_o1, b_o1, w_d, b_d, hidden, vT);
    kv2_kernel<<<dim3(160, NB), 256, 0, stream>>>(hidden, w_o2, b_o2, keyT);

    fused_kernel<<<dim3(NPX / 128, 1, NB), 512, 0, stream>>>(
        wb_p1, x, wb_p2, b_p1, b_p2, keyT, vT, wb_u, b_u, out);
}